// Round 1
// 401.803 us; speedup vs baseline: 1.0039x; 1.0039x over previous
//
#include <hip/hip_runtime.h>
#include <math.h>

#define DEV __device__ __forceinline__

static constexpr int S_LEN  = 2048;
static constexpr int IN_DIM = 1024;
static constexpr int P_DIM  = 512;
static constexpr int NHEAD  = 8;
static constexpr int HD     = 64;
static constexpr int KN     = 128;

typedef __attribute__((ext_vector_type(8))) short bf16x8;
typedef __attribute__((ext_vector_type(4))) float f32x4;

DEV float gelu_exact(float x) {
    return 0.5f * x * (1.0f + erff(x * 0.70710678118654752440f));
}

// float -> bf16 (RNE), and the split residual helpers
DEV short bf_hi(float x) {
    unsigned u = __float_as_uint(x);
    unsigned r = (u + 0x7fffu + ((u >> 16) & 1u)) >> 16;
    return (short)r;
}
DEV float bf_f(short h) { return __uint_as_float(((unsigned)(unsigned short)h) << 16); }

// 256-thread block sum reduction. sm4 must be float[4] shared.
DEV float block_reduce_sum(float v, float* sm4) {
    #pragma unroll
    for (int off = 32; off; off >>= 1) v += __shfl_down(v, off, 64);
    int lane = threadIdx.x & 63, w = threadIdx.x >> 6;
    __syncthreads();
    if (lane == 0) sm4[w] = v;
    __syncthreads();
    return sm4[0] + sm4[1] + sm4[2] + sm4[3];
}

// ---------------- K1: centroids, L2-normalized, split-bf16 [p][d] -----------
__global__ __launch_bounds__(256) void k_cent(const float* __restrict__ penta,
                                              short* __restrict__ ch,
                                              short* __restrict__ cl) {
    int p = blockIdx.x, t = threadIdx.x;
    __shared__ float sm4[4];
    float c0 = 0.f, c1 = 0.f;
    #pragma unroll
    for (int v = 0; v < 5; v++) {
        const float* row = penta + ((long)p * 5 + v) * P_DIM;
        c0 += row[t];
        c1 += row[t + 256];
    }
    c0 /= 5.0f; c1 /= 5.0f;
    float tot = block_reduce_sum(c0 * c0 + c1 * c1, sm4);
    float n = fmaxf(sqrtf(tot), 1e-12f);
    float v0 = c0 / n, v1 = c1 / n;
    short h0 = bf_hi(v0), h1 = bf_hi(v1);
    ch[p * P_DIM + t]       = h0;
    ch[p * P_DIM + t + 256] = h1;
    cl[p * P_DIM + t]       = bf_hi(v0 - bf_f(h0));
    cl[p * P_DIM + t + 256] = bf_hi(v1 - bf_f(h1));
}

// ---------------- weight transpose + split: W (K x N) -> WT_hi/lo (N x K) ---
template <int K, int N>
__global__ __launch_bounds__(256) void k_wt(const float* __restrict__ W,
                                            short* __restrict__ WTh,
                                            short* __restrict__ WTl) {
    __shared__ float tile[64][65];
    int bk = blockIdx.x, bn = blockIdx.y;
    int t = threadIdx.x;
    int c = t & 63, r4 = t >> 6;
    #pragma unroll
    for (int i = 0; i < 16; i++) {
        int row = r4 + i * 4;
        tile[row][c] = W[(long)(bk * 64 + row) * N + bn * 64 + c];
    }
    __syncthreads();
    #pragma unroll
    for (int i = 0; i < 16; i++) {
        int n = r4 + i * 4;
        float v = tile[c][n];
        short h = bf_hi(v);
        long o = (long)(bn * 64 + n) * K + bk * 64 + c;
        WTh[o] = h;
        WTl[o] = bf_hi(v - bf_f(h));
    }
}

// ---------------- MFMA split-bf16 GEMM: C = A@W + bias ----------------------
// BM x 128 block tile (BK=32), 4 waves in 2x2, wave tile (BM/2) x 64.
template <int BM, int K, int N, int EPI, bool SPLITA>
__global__ __launch_bounds__(256) void k_mm(const float* __restrict__ Af,
                                            const short* __restrict__ Ash,
                                            const short* __restrict__ Asl,
                                            const short* __restrict__ BTh,
                                            const short* __restrict__ BTl,
                                            const float* __restrict__ bias,
                                            float* __restrict__ C,
                                            unsigned long long* __restrict__ rowkey) {
    constexpr int TI = BM / 32;   // i-tiles (of 16 rows) per wave
    __shared__ short Ah[BM * 40], Al[BM * 40], Bh[128 * 40], Bl[128 * 40];
    int t = threadIdx.x;
    int lane = t & 63, wave = t >> 6;
    int wr = (wave >> 1) * (BM / 2), wc = (wave & 1) * 64;
    int m = lane & 15, quad = lane >> 4;
    int rb = blockIdx.x * BM, cb = blockIdx.y * 128;

    f32x4 acc[TI][4];
    #pragma unroll
    for (int i = 0; i < TI; i++)
        #pragma unroll
        for (int j = 0; j < 4; j++) acc[i][j] = (f32x4){0.f, 0.f, 0.f, 0.f};

    for (int k0 = 0; k0 < K; k0 += 32) {
        __syncthreads();
        if constexpr (SPLITA) {
            #pragma unroll
            for (int ps = 0; ps < BM / 64; ps++) {
                int idx = t + ps * 256;       // 0..BM*4-1
                int row = idx >> 2, c4 = idx & 3;
                *(float4*)(Ah + row * 40 + c4 * 8) =
                    *(const float4*)(Ash + (long)(rb + row) * K + k0 + c4 * 8);
                *(float4*)(Al + row * 40 + c4 * 8) =
                    *(const float4*)(Asl + (long)(rb + row) * K + k0 + c4 * 8);
            }
        } else {
            #pragma unroll
            for (int ps = 0; ps < BM / 32; ps++) {
                int row = (t >> 3) + ps * 32;
                int seg = t & 7;
                float4 v = *(const float4*)(Af + (long)(rb + row) * K + k0 + seg * 4);
                short h0 = bf_hi(v.x), h1 = bf_hi(v.y), h2 = bf_hi(v.z), h3 = bf_hi(v.w);
                short l0 = bf_hi(v.x - bf_f(h0)), l1 = bf_hi(v.y - bf_f(h1));
                short l2 = bf_hi(v.z - bf_f(h2)), l3 = bf_hi(v.w - bf_f(h3));
                *(short4*)(Ah + row * 40 + seg * 4) = make_short4(h0, h1, h2, h3);
                *(short4*)(Al + row * 40 + seg * 4) = make_short4(l0, l1, l2, l3);
            }
        }
        #pragma unroll
        for (int ps = 0; ps < 2; ps++) {
            int row = (t >> 2) + ps * 64;
            int seg = t & 3;
            *(float4*)(Bh + row * 40 + seg * 8) =
                *(const float4*)(BTh + (long)(cb + row) * K + k0 + seg * 8);
            *(float4*)(Bl + row * 40 + seg * 8) =
                *(const float4*)(BTl + (long)(cb + row) * K + k0 + seg * 8);
        }
        __syncthreads();

        bf16x8 ah[TI], al[TI], bh[4], bl[4];
        #pragma unroll
        for (int i = 0; i < TI; i++) {
            ah[i] = *(const bf16x8*)(Ah + (wr + i * 16 + m) * 40 + quad * 8);
            al[i] = *(const bf16x8*)(Al + (wr + i * 16 + m) * 40 + quad * 8);
        }
        #pragma unroll
        for (int j = 0; j < 4; j++) {
            bh[j] = *(const bf16x8*)(Bh + (wc + j * 16 + m) * 40 + quad * 8);
            bl[j] = *(const bf16x8*)(Bl + (wc + j * 16 + m) * 40 + quad * 8);
        }
        #pragma unroll
        for (int i = 0; i < TI; i++)
            #pragma unroll
            for (int j = 0; j < 4; j++) {
                acc[i][j] = __builtin_amdgcn_mfma_f32_16x16x32_bf16(ah[i], bh[j], acc[i][j], 0, 0, 0);
                acc[i][j] = __builtin_amdgcn_mfma_f32_16x16x32_bf16(ah[i], bl[j], acc[i][j], 0, 0, 0);
                acc[i][j] = __builtin_amdgcn_mfma_f32_16x16x32_bf16(al[i], bh[j], acc[i][j], 0, 0, 0);
            }
    }

    if (EPI == 0) {
        #pragma unroll
        for (int i = 0; i < TI; i++) {
            int gr0 = rb + wr + i * 16 + quad * 4;
            #pragma unroll
            for (int j = 0; j < 4; j++) {
                int gc = cb + wc + j * 16 + m;
                float bv = bias[gc];
                #pragma unroll
                for (int r = 0; r < 4; r++)
                    C[(long)(gr0 + r) * N + gc] = acc[i][j][r] + bv;
            }
        }
    } else {
        #pragma unroll
        for (int i = 0; i < TI; i++) {
            #pragma unroll
            for (int r = 0; r < 4; r++) {
                int gr = rb + wr + i * 16 + quad * 4 + r;
                float bv = acc[i][0][r];
                int bp = cb + wc + m;
                #pragma unroll
                for (int j = 1; j < 4; j++) {
                    float v = acc[i][j][r];
                    int p = cb + wc + j * 16 + m;   // ascending; > keeps lowest p
                    if (v > bv) { bv = v; bp = p; }
                }
                #pragma unroll
                for (int off = 1; off < 16; off <<= 1) {
                    float ov = __shfl_xor(bv, off, 64);
                    int op = __shfl_xor(bp, off, 64);
                    if (ov > bv || (ov == bv && op < bp)) { bv = ov; bp = op; }
                }
                if (m == 0) {
                    unsigned u = __float_as_uint(bv);
                    u = (u & 0x80000000u) ? ~u : (u | 0x80000000u);
                    unsigned long long key =
                        ((unsigned long long)u << 32) | (unsigned)(0xFFFFFFFFu - (unsigned)bp);
                    atomicMax(&rowkey[gr], key);
                }
            }
        }
    }
}

// ---------------- K3: LayerNorm -> gelu -> L2 norm -> emit SPLIT bf16 -------
__global__ __launch_bounds__(256) void k_ln_gelu_norm(const float* __restrict__ Zin,
                                                      const float* __restrict__ g,
                                                      const float* __restrict__ b,
                                                      short* __restrict__ z_h,
                                                      short* __restrict__ z_l) {
    long row = blockIdx.x;
    int t = threadIdx.x;
    __shared__ float sm4[4];
    float x0 = Zin[row * P_DIM + t], x1 = Zin[row * P_DIM + t + 256];
    float mu = block_reduce_sum(x0 + x1, sm4) * (1.0f / P_DIM);
    float d0 = x0 - mu, d1 = x1 - mu;
    float var = block_reduce_sum(d0 * d0 + d1 * d1, sm4) * (1.0f / P_DIM);
    float rs = 1.0f / sqrtf(var + 1e-5f);
    float y0 = gelu_exact(d0 * rs * g[t] + b[t]);
    float y1 = gelu_exact(d1 * rs * g[t + 256] + b[t + 256]);
    float nn = block_reduce_sum(y0 * y0 + y1 * y1, sm4);
    float n = fmaxf(sqrtf(nn), 1e-12f);
    float v0 = y0 / n, v1 = y1 / n;
    short h0 = bf_hi(v0), h1 = bf_hi(v1);
    z_h[row * P_DIM + t]       = h0;
    z_h[row * P_DIM + t + 256] = h1;
    z_l[row * P_DIM + t]       = bf_hi(v0 - bf_f(h0));
    z_l[row * P_DIM + t + 256] = bf_hi(v1 - bf_f(h1));
}

// ---------------- K5: bitonic argsort (fused rowkey->pos gather) ------------
__global__ __launch_bounds__(256) void k_sort(const unsigned long long* __restrict__ rowkey,
                                              const float* __restrict__ spos,
                                              int* __restrict__ order,
                                              float* __restrict__ pos_srt) {
    int b = blockIdx.x, t = threadIdx.x;
    __shared__ unsigned long long key[2048];
    for (int u = 0; u < 8; u++) {
        int i = t + u * 256;
        unsigned p = 0xFFFFFFFFu - (unsigned)(rowkey[b * 2048 + i] & 0xFFFFFFFFull);
        float pv = spos[p];
        key[i] = (((unsigned long long)__float_as_uint(pv)) << 32) | (unsigned)i;
    }
    __syncthreads();
    for (int k = 2; k <= 2048; k <<= 1) {
        for (int j = k >> 1; j > 0; j >>= 1) {
            for (int u = 0; u < 8; u++) {
                int i = t + u * 256;
                int l = i ^ j;
                if (l > i) {
                    bool up = ((i & k) == 0);
                    unsigned long long a = key[i], c = key[l];
                    if ((a > c) == up) { key[i] = c; key[l] = a; }
                }
            }
            __syncthreads();
        }
    }
    for (int u = 0; u < 8; u++) {
        int r = t + u * 256;
        unsigned long long kk = key[r];
        order[b * 2048 + r]   = (int)(kk & 0xffffffffu);
        pos_srt[b * 2048 + r] = __uint_as_float((unsigned)(kk >> 32));
    }
}

// ---------------- K6: exact top-128, one WAVE per query ---------------------
__global__ __launch_bounds__(256) void k_routes(const float* __restrict__ pos_srt,
                                                const int* __restrict__ order,
                                                unsigned long long* __restrict__ bmG,
                                                uint2* __restrict__ bounds) {
    int blk = blockIdx.x;                 // 1024 blocks, 4 queries (waves) each
    int b = blk >> 9;
    int t = threadIdx.x;
    int lane = t & 63, wave = t >> 6;
    int r = (blk & 511) * 4 + wave;       // query rank in [0,2048)
    __shared__ float ps[2048];
    __shared__ unsigned short tk[2048];
    for (int u = 0; u < 8; u++) {
        int i = t + u * 256;
        ps[i] = pos_srt[b * 2048 + i];
        tk[i] = (unsigned short)order[b * 2048 + i];
    }
    __syncthreads();

    float pi = ps[r];
    float T = 3e38f;
    #pragma unroll
    for (int a2 = 0; a2 < 2; a2++) {
        int a = lane + a2 * 64;           // 0..127
        int jl = r - a, jr = r + 127 - a;
        if (jl >= 0 && jr <= 2047) {
            float dl = (a > 0)   ? (pi - ps[jl]) : 0.f;
            float dr = (a < 127) ? (ps[jr] - pi) : 0.f;
            T = fminf(T, fmaxf(dl, dr));
        }
    }
    #pragma unroll
    for (int off = 1; off < 64; off <<= 1) T = fminf(T, __shfl_xor(T, off, 64));

    int lo = 0, hi = r;
    while (lo < hi) { int mid = (lo + hi) >> 1; if (pi - ps[mid] <= T) hi = mid; else lo = mid + 1; }
    int mn = lo;
    lo = r; hi = 2047;
    while (lo < hi) { int mid = (lo + hi + 1) >> 1; if (ps[mid] - pi <= T) lo = mid; else hi = mid - 1; }
    int mx = lo;
    int Ls, Rs;
    if (T > 0.f) {
        lo = 0; hi = r;
        while (lo < hi) { int mid = (lo + hi) >> 1; if (pi - ps[mid] < T) hi = mid; else lo = mid + 1; }
        Ls = lo;
        lo = r; hi = 2047;
        while (lo < hi) { int mid = (lo + hi + 1) >> 1; if (ps[mid] - pi < T) lo = mid; else hi = mid - 1; }
        Rs = lo;
    } else { Ls = r + 1; Rs = r - 1; }

    int cnt_strict = (Rs >= Ls) ? (Rs - Ls + 1) : 0;
    int need = 128 - cnt_strict;
    int l0a, l0b, r0a, r0b;
    if (cnt_strict > 0) { l0a = mn; l0b = Ls - 1; r0a = Rs + 1; r0b = mx; }
    else                { l0a = mn; l0b = mx;     r0a = 1;      r0b = 0; }
    int nL = (l0b >= l0a) ? (l0b - l0a + 1) : 0;
    int nR = (r0b >= r0a) ? (r0b - r0a + 1) : 0;
    int tiecount = nL + nR;

    int X = 65535;
    if (need < tiecount) {
        int lo2 = 0, hi2 = 2047;
        while (lo2 < hi2) {
            int mid = (lo2 + hi2) >> 1;
            int cnt = 0;
            for (int e = lane; e < tiecount; e += 64) {
                int j = (e < nL) ? (l0a + e) : (r0a + e - nL);
                cnt += (tk[j] <= mid) ? 1 : 0;
            }
            #pragma unroll
            for (int off = 1; off < 64; off <<= 1) cnt += __shfl_xor(cnt, off, 64);
            if (cnt >= need) hi2 = mid; else lo2 = mid + 1;
        }
        X = lo2;
    }

    int qlo_loc = 1 << 30, qhi_loc = -1;
    if (lane < 32) {
        unsigned long long bits = 0;
        int j0 = lane << 6, j1 = j0 + 63;
        if (cnt_strict > 0) {
            int a0 = max(Ls, j0), a1 = min(Rs, j1);
            if (a0 <= a1) {
                int s = a0 - j0, e = a1 - j0;
                unsigned long long msk = (e - s == 63) ? ~0ull
                                       : (((1ull << (e - s + 1)) - 1) << s);
                bits |= msk;
            }
        }
        int a0 = max(l0a, j0), a1 = min(l0b, j1);
        for (int j = a0; j <= a1; j++) if (tk[j] <= X) bits |= 1ull << (j - j0);
        a0 = max(r0a, j0); a1 = min(r0b, j1);
        for (int j = a0; j <= a1; j++) if (tk[j] <= X) bits |= 1ull << (j - j0);
        if (bits) {
            qlo_loc = j0 + __builtin_ctzll(bits);
            qhi_loc = j0 + 63 - __builtin_clzll(bits);
        }
        bmG[((long)(b * 2048 + r)) * 32 + lane] = bits;
    }
    #pragma unroll
    for (int off = 1; off < 64; off <<= 1) {
        qlo_loc = min(qlo_loc, __shfl_xor(qlo_loc, off, 64));
        qhi_loc = max(qhi_loc, __shfl_xor(qhi_loc, off, 64));
    }
    if (lane == 0)
        bounds[b * 2048 + r] = make_uint2((unsigned)qlo_loc, (unsigned)qhi_loc);
}

// ---------------- K6b: K prep — sorted, split bf16, [b][rank][512] ----------
__global__ __launch_bounds__(256) void k_kprep(const float* __restrict__ qkv,
                                               const int* __restrict__ order,
                                               short* __restrict__ Ks_h,
                                               short* __restrict__ Ks_l) {
    int b = blockIdx.y;
    int t = threadIdx.x;
    int lr = t >> 5;                       // 8 ranks per block
    int seg = t & 31;                      // 16 floats per seg
    int rank = blockIdx.x * 8 + lr;
    int tok = order[b * 2048 + rank];
    const float4* src = (const float4*)qkv + (long)(b * 2048 + tok) * 384 + 128 + seg * 4;
    long dsto = (long)(b * 2048 + rank) * 512 + seg * 16;
    #pragma unroll
    for (int u = 0; u < 4; u++) {
        float4 v = src[u];
        short h0 = bf_hi(v.x), h1 = bf_hi(v.y), h2 = bf_hi(v.z), h3 = bf_hi(v.w);
        *(short4*)(Ks_h + dsto + u * 4) = make_short4(h0, h1, h2, h3);
        *(short4*)(Ks_l + dsto + u * 4) =
            make_short4(bf_hi(v.x - bf_f(h0)), bf_hi(v.y - bf_f(h1)),
                        bf_hi(v.z - bf_f(h2)), bf_hi(v.w - bf_f(h3)));
    }
}

// ---------------- K6c: V prep — sorted, transposed bf16-hi, [b][d][rank] ----
__global__ __launch_bounds__(256) void k_vprep(const float* __restrict__ qkv,
                                               const int* __restrict__ order,
                                               short* __restrict__ Vt_h) {
    __shared__ short tile[64][72];
    int rt = blockIdx.x, dt = blockIdx.y, b = blockIdx.z;
    int t = threadIdx.x;
    int lr = t >> 2;                       // rank within tile
    int q4 = t & 3;
    int tok = order[b * 2048 + rt * 64 + lr];
    const float4* src = (const float4*)qkv + (long)(b * 2048 + tok) * 384 + 256 + dt * 16;
    #pragma unroll
    for (int u = 0; u < 4; u++) {
        float4 v = src[q4 + u * 4];
        int d0 = (q4 + u * 4) * 4;
        tile[d0 + 0][lr] = bf_hi(v.x);
        tile[d0 + 1][lr] = bf_hi(v.y);
        tile[d0 + 2][lr] = bf_hi(v.z);
        tile[d0 + 3][lr] = bf_hi(v.w);
    }
    __syncthreads();
    int d = t >> 2, c4 = t & 3;
    long o = ((long)(b * 512 + dt * 64 + d)) * 2048 + rt * 64 + c4 * 16;
    #pragma unroll
    for (int j = 0; j < 4; j++)
        *(short4*)(Vt_h + o + j * 4) = make_short4(tile[d][c4 * 16 + j * 4 + 0],
                                                   tile[d][c4 * 16 + j * 4 + 1],
                                                   tile[d][c4 * 16 + j * 4 + 2],
                                                   tile[d][c4 * 16 + j * 4 + 3]);
}

// ---------------- K7: MFMA flash attention (direct-global K/V) --------------
__global__ __launch_bounds__(256) void k_attn(const float* __restrict__ qkv,
                                              const int* __restrict__ order,
                                              const unsigned long long* __restrict__ bmG,
                                              const uint2* __restrict__ bounds,
                                              const short* __restrict__ Ks_h,
                                              const short* __restrict__ Ks_l,
                                              const short* __restrict__ Vt_h,
                                              short* __restrict__ attn_h,
                                              short* __restrict__ attn_l) {
    __shared__ __align__(16) char smem[17024];
    short* Pt = (short*)smem;                               // 4 waves x 1280 shorts
    unsigned short* cm = (unsigned short*)(smem + 10240);   // 128 x 16
    float* Opart = (float*)smem;                            // alias: [2][16][128]
    float2* ml = (float2*)(smem + 16384);                   // [2][2][16]
    int* sh_tok = (int*)(smem + 16896);                     // 16
    int* sh_lohi = (int*)(smem + 16960);                    // 2

    int gb = blockIdx.x;
    int b  = gb >> 9;
    int qg = (gb >> 2) & 127;
    int hp = gb & 3;
    int h0 = hp * 2;
    int r0 = qg * 16;
    int t = threadIdx.x;
    int lane = t & 63, wave = t >> 6;
    int rh = wave & 1, hs = wave >> 1;
    int key = lane & 15, quad = lane >> 4;

    const float4* qkvF4 = (const float4*)qkv;

    if (t < 16) sh_tok[t] = order[b * 2048 + r0 + t];
    if (t == 0) { sh_lohi[0] = 1 << 30; sh_lohi[1] = 0; }
    #pragma unroll
    for (int u = 0; u < 8; u++) {
        int e = t + u * 256;
        int c = e >> 4, q = e & 15;
        cm[c * 16 + q] = (unsigned short)(
            (bmG[((long)(b * 2048 + r0 + q)) * 32 + (c >> 2)] >> ((c & 3) * 16)) & 0xFFFF);
    }
    __syncthreads();
    if (t < 16) {
        uint2 bd = bounds[b * 2048 + r0 + t];
        atomicMin(&sh_lohi[0], (int)bd.x);
        atomicMax(&sh_lohi[1], (int)bd.y);
    }

    bf16x8 qh[2], ql[2];
    {
        long tq = (long)(b * 2048 + sh_tok[key]) * 384;
        #pragma unroll
        for (int ks = 0; ks < 2; ks++) {
            float4 v0 = qkvF4[tq + (h0 + hs) * 16 + ks * 8 + quad * 2];
            float4 v1 = qkvF4[tq + (h0 + hs) * 16 + ks * 8 + quad * 2 + 1];
            float vv[8] = {v0.x, v0.y, v0.z, v0.w, v1.x, v1.y, v1.z, v1.w};
            #pragma unroll
            for (int j = 0; j < 8; j++) {
                short hb = bf_hi(vv[j]);
                qh[ks][j] = hb;
                ql[ks][j] = bf_hi(vv[j] - bf_f(hb));
            }
        }
    }
    __syncthreads();
    int lo = sh_lohi[0] & ~63, hi = sh_lohi[1] + 1;

    float mrow[4], lrow[4];
    f32x4 Ont[4];
    #pragma unroll
    for (int r = 0; r < 4; r++) { mrow[r] = -1e30f; lrow[r] = 0.f; }
    #pragma unroll
    for (int nt = 0; nt < 4; nt++) Ont[nt] = (f32x4){0.f, 0.f, 0.f, 0.f};

    short* PtH = Pt + wave * 1280;
    short* PtL = PtH + 640;

    int hd = h0 + hs;
    long kbase = ((long)b * 2048) * 512 + hd * 64 + quad * 8;   // + rank*512 + ks*32
    long vbase = ((long)(b * 512 + hd * 64 + key)) * 2048;      // + nt*16*2048 + rank

    // NOTE: no __syncthreads() in this loop — waves run fully independently.
    for (int c0 = lo; c0 < hi; c0 += 64) {
        int cb = c0 + rh * 32;
        if (cb >= hi) continue;                  // wave-uniform
        int ch0 = cb >> 4;
        unsigned long long m0 = *(const unsigned long long*)(cm + ch0 * 16 + quad * 4);
        unsigned long long m1 = (ch0 + 1 < 128)
            ? *(const unsigned long long*)(cm + (ch0 + 1) * 16 + quad * 4) : 0ull;
        if (!__any((m0 | m1) != 0ull)) continue; // wave-uniform skip

        // cb <= 2016 (multiple of 32, < hi <= 2048) so cb+31 <= 2047: in-bounds.
        long kr0 = kbase + (long)(cb + key) * 512;
        long kr1 = kbase + (long)(cb + 16 + key) * 512;

        f32x4 S0 = (f32x4){0.f,0.f,0.f,0.f}, S1 = (f32x4){0.f,0.f,0.f,0.f};
        #pragma unroll
        for (int ks = 0; ks < 2; ks++) {
            bf16x8 b0h = *(const bf16x8*)(Ks_h + kr0 + ks * 32);
            bf16x8 b0l = *(const bf16x8*)(Ks_l + kr0 + ks * 32);
            bf16x8 b1h = *(const bf16x8*)(Ks_h + kr1 + ks * 32);
            bf16x8 b1l = *(const bf16x8*)(Ks_l + kr1 + ks * 32);
            S0 = __builtin_amdgcn_mfma_f32_16x16x32_bf16(qh[ks], b0h, S0, 0, 0, 0);
            S0 = __builtin_amdgcn_mfma_f32_16x16x32_bf16(qh[ks], b0l, S0, 0, 0, 0);
            S0 = __builtin_amdgcn_mfma_f32_16x16x32_bf16(ql[ks], b0h, S0, 0, 0, 0);
            S1 = __builtin_amdgcn_mfma_f32_16x16x32_bf16(qh[ks], b1h, S1, 0, 0, 0);
            S1 = __builtin_amdgcn_mfma_f32_16x16x32_bf16(qh[ks], b1l, S1, 0, 0, 0);
            S1 = __builtin_amdgcn_mfma_f32_16x16x32_bf16(ql[ks], b1h, S1, 0, 0, 0);
        }
        float s0[4], s1[4], p0[4], p1[4];
        unsigned bit0[4], bit1[4];
        #pragma unroll
        for (int r = 0; r < 4; r++) {
            bit0[r] = (unsigned)((m0 >> (r * 16 + key)) & 1);
            bit1[r] = (unsigned)((m1 >> (r * 16 + key)) & 1);
            s0[r] = bit0[r] ? S0[r] * 0.125f : -1e30f;
            s1[r] = bit1[r] ? S1[r] * 0.125f : -1e30f;
        }
        #pragma unroll
        for (int r = 0; r < 4; r++) {
            float cmax = fmaxf(s0[r], s1[r]);
            cmax = fmaxf(cmax, __shfl_xor(cmax, 1, 64));
            cmax = fmaxf(cmax, __shfl_xor(cmax, 2, 64));
            cmax = fmaxf(cmax, __shfl_xor(cmax, 4, 64));
            cmax = fmaxf(cmax, __shfl_xor(cmax, 8, 64));
            float mn = fmaxf(mrow[r], cmax);
            float alpha = __expf(mrow[r] - mn);
            mrow[r] = mn;
            p0[r] = bit0[r] ? __expf(s0[r] - mn) : 0.f;
            p1[r] = bit1[r] ? __expf(s1[r] - mn) : 0.f;
            float rs = p0[r] + p1[r];
            rs += __shfl_xor(rs, 1, 64);
            rs += __shfl_xor(rs, 2, 64);
            rs += __shfl_xor(rs, 4, 64);
            rs += __shfl_xor(rs, 8, 64);
            lrow[r] = lrow[r] * alpha + rs;
            #pragma unroll
            for (int nt = 0; nt < 4; nt++) Ont[nt][r] *= alpha;
        }
        #pragma unroll
        for (int r = 0; r < 4; r++) {
            short ha = bf_hi(p0[r]);
            PtH[(quad * 4 + r) * 40 + key] = ha;
            PtL[(quad * 4 + r) * 40 + key] = bf_hi(p0[r] - bf_f(ha));
            short hb = bf_hi(p1[r]);
            PtH[(quad * 4 + r) * 40 + 16 + key] = hb;
            PtL[(quad * 4 + r) * 40 + 16 + key] = bf_hi(p1[r] - bf_f(hb));
        }
        bf16x8 pfh = *(const bf16x8*)(PtH + key * 40 + quad * 8);
        bf16x8 pfl = *(const bf16x8*)(PtL + key * 40 + quad * 8);
        #pragma unroll
        for (int nt = 0; nt < 4; nt++) {
            bf16x8 vf = *(const bf16x8*)(Vt_h + vbase + (long)nt * 16 * 2048
                                         + cb + quad * 8);
            Ont[nt] = __builtin_amdgcn_mfma_f32_16x16x32_bf16(pfh, vf, Ont[nt], 0, 0, 0);
            Ont[nt] = __builtin_amdgcn_mfma_f32_16x16x32_bf16(pfl, vf, Ont[nt], 0, 0, 0);
        }
    }

    if (key == 0) {
        #pragma unroll
        for (int r = 0; r < 4; r++)
            ml[(rh * 2 + hs) * 16 + quad * 4 + r] = make_float2(mrow[r], lrow[r]);
    }
    __syncthreads();   // all waves done with cm/Pt; Opart may now alias them
    #pragma unroll
    for (int nt = 0; nt < 4; nt++)
        #pragma unroll
        for (int r = 0; r < 4; r++)
            Opart[rh * 2048 + (quad * 4 + r) * 128 + hs * 64 + nt * 16 + key] = Ont[nt][r];
    __syncthreads();

    {
        int q = t >> 4, hs2 = (t >> 3) & 1, ds = t & 7;
        float2 a = ml[(0 * 2 + hs2) * 16 + q];
        float2 c = ml[(1 * 2 + hs2) * 16 + q];
        float M = fmaxf(a.x, c.x);
        float w0 = __expf(a.x - M), w1 = __expf(c.x - M);
        float denom = a.y * w0 + c.y * w1;
        float inv = 1.0f / fmaxf(denom, 1e-37f);
        long off = (long)(b * 2048 + sh_tok[q]) * P_DIM + (h0 + hs2) * HD + ds * 8;
        short hsv[8], lsv[8];
        #pragma unroll
        for (int j = 0; j < 8; j++) {
            int d = hs2 * 64 + ds * 8 + j;
            float o = (Opart[q * 128 + d] * w0 + Opart[2048 + q * 128 + d] * w1) * inv;
            hsv[j] = bf_hi(o);
            lsv[j] = bf_hi(o - bf_f(hsv[j]));
        }
        *(short4*)(attn_h + off)     = make_short4(hsv[0], hsv[1], hsv[2], hsv[3]);
        *(short4*)(attn_h + off + 4) = make_short4(hsv[4], hsv[5], hsv[6], hsv[7]);
        *(short4*)(attn_l + off)     = make_short4(lsv[0], lsv[1], lsv[2], lsv[3]);
        *(short4*)(attn_l + off + 4) = make_short4(lsv[4], lsv[5], lsv[6], lsv[7]);
    }
}

// ---------------- K9: pooled partial sums (atomic) --------------------------
__global__ __launch_bounds__(256) void k_pool(const float* __restrict__ zatt,
                                              float* __restrict__ pooled) {
    int b = blockIdx.y, chunk = blockIdx.x, t = threadIdx.x;
    float a0 = 0.f, a1 = 0.f;
    for (int s = 0; s < 16; s++) {
        long row = ((long)b * S_LEN + chunk * 16 + s) * P_DIM;
        a0 += zatt[row + t];
        a1 += zatt[row + t + 256];
    }
    atomicAdd(&pooled[b * P_DIM + t], a0);
    atomicAdd(&pooled[b * P_DIM + t + 256], a1);
}

// ---------------- Expert stage 1: h = pooled/S @ w1 + b1 (all 3 experts) ----
__global__ __launch_bounds__(256) void k_exp_fc1(const float* __restrict__ pooled,
                                                 const float* __restrict__ w1_0, const float* __restrict__ b1_0,
                                                 const float* __restrict__ w1_1, const float* __restrict__ b1_1,
                                                 const float* __restrict__ w1_2, const float* __restrict__ b1_2,
                                                 float* __restrict__ h) {
    int t = threadIdx.x, b = blockIdx.y;
    int c = blockIdx.x * 256 + t;  // [0, 1792)
    __shared__ float pl[P_DIM];
    pl[t]       = pooled[b * P_DIM + t]       * (1.0f / S_LEN);
    pl[t + 256] = pooled[b * P_DIM + t + 256] * (1.0f / S_LEN);
    __syncthreads();

    const float* wp; const float* bp; int s2, j;
    if (c < 256)      { wp = w1_0; bp = b1_0; s2 = 256;  j = c; }
    else if (c < 768) { wp = w1_1; bp = b1_1; s2 = 512;  j = c - 256; }
    else              { wp = w1_2; bp = b1_2; s2 = 1024; j = c - 768; }

    const float* p = wp + j;
    float acc = 0.f;
    #pragma unroll 16
    for (int k = 0; k < P_DIM; k++) {
        acc = fmaf(pl[k], *p, acc);
        p += s2;
    }
    h[(long)b * 1792 + c] = acc + bp[j];
}

// ---------------- Expert stage 2: LN + gelu per (expert, batch) -------------
__global__ __launch_bounds__(256) void k_exp_ln(float* __restrict__ h,
                                                const float* __restrict__ g0, const float* __restrict__ bb0,
                                                const float* __restrict__ g1, const float* __restrict__ bb1,
                                                const float* __restrict__ g2, const float* __restrict__ bb2) {
    int e = blockIdx.x, b = blockIdx.y, t = threadIdx.x;
    __shared__ float sm4[4];
    const int offs[3] = {0, 256, 768};
    const int ns[3]   = {256, 512, 1024};
    const float* gs[3]  = {g0, g1, g2};
    const float* bbs[3] = {bb0, bb1, bb2};
    int n = ns[e];
    float* hp = h + (long)b * 1792 + offs[e];
    const float* g = gs[e]; const float* bb = bbs[e];

    float x[4];
    float loc = 0.f;
    for (int u = 0; u < 4; u++) {
        int j = t + u * 256;
        x[u] = (j < n) ? hp[j] : 0.f;
        loc += x[u];
    }
    float mu = block_reduce_sum(loc, sm4) / (float)n;
    loc = 0.f;
    for (int u = 0; u < 4; u++) {
        int j = t + u * 256;
        if (j < n) { float d = x[u] - mu; loc += d * d; }
    }
    float var = block_reduce_sum(loc, sm4) / (float)n;
    float rs = 1.0f / sqrtf(var + 1e-5f);
    for (int u = 0; u < 4; u++) {
        int j = t + u * 256;
        if (j < n) hp[j] = gelu_exact((x[u] - mu) * rs * g[j] + bb[j]);
    }
}

// ---------------- Expert stage 3: out = h @ w2 + b2 (all 3 experts) ---------
__global__ __launch_bounds__(256) void k_exp_fc2(const float* __restrict__ h,
                                                 const float* __restrict__ w2_0, const float* __restrict__ b2_0,
                                                 const float* __restrict__ w2_1, const float* __restrict__ b2_1,
                                                 const float* __restrict__ w2_2, const float* __restrict__ b2_2,
                                                 float* __restrict__ out) {
    int t = threadIdx.x, b = blockIdx.y;
    int c = blockIdx.x * 256 + t;  // [0, 1024), valid < 896
    __shared__ float hs[1792];
    for (int u = 0; u < 7; u++) hs[t + u * 256] = h[(long)b * 1792 + t + u * 256];
    __syncthreads();
    if (c >= 896) return;

    const float* wp; const float* bp; int s2, sN, j, off_h;
    if (c < 128)      { wp = w2_0; bp = b2_0; s2 = 256;  sN = 128; j = c;       off_h = 0; }
    else if (c < 384) { wp = w2_1; bp = b2_1; s2 = 512;  sN = 256; j = c - 128; off_h = 256; }
    else              { wp = w2_2; bp = b2_2; s2 = 1024; sN = 512; j = c - 384; off_h = 768; }

    const float* p = wp + j;
    const float* hh = hs + off_h;
    float acc = 0.f;
    #pragma unroll 16
    for (int k = 0; k < s2; k++) {
        acc = fmaf(hh[k], *p, acc);
        p += sN;
    }
    out[b * 896 + c] = acc + bp[j];
}

// ---------------------------------------------------------------------------
extern "C" void kernel_launch(void* const* d_in, const int* in_sizes, int n_in,
                              void* d_out, int out_size, void* d_ws, size_t ws_size,
                              hipStream_t stream) {
    const float* seq   = (const float*)d_in[0];
    const float* penta = (const float*)d_in[1];
    const float* spos  = (const float*)d_in[2];
    const float* projW = (const float*)d_in[3];
    const float* projb = (const float*)d_in[4];
    const float* lng   = (const float*)d_in[5];
    const float* lnb   = (const float*)d_in[6];
    const float* qkvW  = (const float*)d_in[7];
    const float* qkvb  = (const float*)d_in[8];
    const float* outW  = (const float*)d_in[9];
    const float* outb  = (const float*)d_in[10];

    float* ws      = (float*)d_ws;
    float* z_pre   = ws;                      // 2097152 floats (zatt / Ks alias)
    short* z_h     = (short*)(z_pre + 2097152); // 2097152 shorts (attn_h alias)
    short* z_l     = z_h + 2097152;           // 2097152 shorts (attn_l alias)
    float* qkv     = (float*)(z_l + 2097152); // 6291456 floats
    float* pos     = qkv + 6291456;           // 4096 (unused, layout keep)
    float* pooled  = pos + 4096;              // 1024
    float* hbuf    = pooled + 1024;           // 4096
    unsigned long long* rowkey = (unsigned long long*)(hbuf + 4096);  // 4096 ull
    float* pos_srt = (float*)(rowkey + 4096); // 4096
    int*   order   = (int*)(pos_srt + 4096);  // 4096
    uint2* bounds  = (uint2*)(order + 4096);  // 4096 uint2
    unsigned long long* bmG = (unsigned long long*)(bounds + 4096); // 131072 ull
    short* cent_h  = (short*)(bmG + 131072);  // 524288 shorts
    short* cent_l  = cent_h + 524288;
    short* pjWT_h  = cent_l + 524288;         // 512x1024
    short* pjWT_l  = pjWT_h + 524288;
    short* qkWT_h  = pjWT_l + 524288;         // 1536x512
    short* qkWT_l  = qkWT_h + 786432;
    short* owWT_h  = qkWT_l + 786432;         // 512x512
    short* owWT_l  = owWT_h + 262144;
    short* attn_h  = z_h;     // z_h/z_l dead after anchor+qkv GEMMs
    short* attn_l  = z_l;
    float* zatt    = z_pre;   // z_pre dead after ln_gelu (until out-proj)

    // K/V prep buffers (alias dead regions; all consumed before their hosts
    // are written again):
    //   Ks_h/Ks_l  <- z_pre (8 MB): dead between k_ln_gelu_norm and out-proj,
    //                which writes zatt only AFTER k_attn completes (in-stream).
    //   Vt_h       <- cent_h..pjWT_l (4 MB): dead after anchor + proj GEMMs.
    short* Ks_h = (short*)z_pre;              // 2 x 2048 x 512
    short* Ks_l = Ks_h + 2097152;
    short* Vt_h = cent_h;                     // 2 x 512 x 2048

    // weight prep
    k_cent<<<1024, 256, 0, stream>>>(penta, cent_h, cent_l);
    { dim3 g(16, 8);  k_wt<IN_DIM, P_DIM><<<g, 256, 0, stream>>>(projW, pjWT_h, pjWT_l); }
    { dim3 g(8, 24);  k_wt<P_DIM, 3 * P_DIM><<<g, 256, 0, stream>>>(qkvW, qkWT_h, qkWT_l); }
    { dim3 g(8, 8);   k_wt<P_DIM, P_DIM><<<g, 256, 0, stream>>>(outW, owWT_h, owWT_l); }

    // proj -> ln/gelu/norm (emits pre-split z)
    { dim3 g(64, 4);  k_mm<64, IN_DIM, P_DIM, 0, false><<<g, 256, 0, stream>>>(
          seq, nullptr, nullptr, pjWT_h, pjWT_l, projb, z_pre, nullptr); }
    k_ln_gelu_norm<<<4096, 256, 0, stream>>>(z_pre, lng, lnb, z_h, z_l);

    // anchor argmax -> sort (fused position gather)
    hipMemsetAsync(rowkey, 0, 4096 * sizeof(unsigned long long), stream);
    { dim3 g(64, 8);  k_mm<64, P_DIM, 1024, 1, true><<<g, 256, 0, stream>>>(
          nullptr, z_h, z_l, cent_h, cent_l, nullptr, nullptr, rowkey); }
    k_sort<<<2, 256, 0, stream>>>(rowkey, spos, order, pos_srt);

    // qkv -> routes(bitmap) -> K/V prep -> attention -> out-proj
    { dim3 g(64, 12); k_mm<64, P_DIM, 3 * P_DIM, 0, true><<<g, 256, 0, stream>>>(
          nullptr, z_h, z_l, qkWT_h, qkWT_l, qkvb, qkv, nullptr); }
    k_routes<<<1024, 256, 0, stream>>>(pos_srt, order, bmG, bounds);
    { dim3 g(256, 2); k_kprep<<<g, 256, 0, stream>>>(qkv, order, Ks_h, Ks_l); }
    { dim3 g(32, 8, 2); k_vprep<<<g, 256, 0, stream>>>(qkv, order, Vt_h); }
    k_attn<<<1024, 256, 0, stream>>>(qkv, order, bmG, bounds,
                                     Ks_h, Ks_l, Vt_h, attn_h, attn_l);
    { dim3 g(64, 4);  k_mm<64, P_DIM, P_DIM, 0, true><<<g, 256, 0, stream>>>(
          nullptr, attn_h, attn_l, owWT_h, owWT_l, outb, zatt, nullptr); }

    // pool + experts
    hipMemsetAsync(pooled, 0, 1024 * sizeof(float), stream);
    { dim3 pg(128, 2); k_pool<<<pg, 256, 0, stream>>>(zatt, pooled); }

    dim3 g1(7, 2);
    k_exp_fc1<<<g1, 256, 0, stream>>>(pooled,
        (const float*)d_in[11], (const float*)d_in[12],
        (const float*)d_in[17], (const float*)d_in[18],
        (const float*)d_in[23], (const float*)d_in[24], hbuf);
    dim3 g2(3, 2);
    k_exp_ln<<<g2, 256, 0, stream>>>(hbuf,
        (const float*)d_in[13], (const float*)d_in[14],
        (const float*)d_in[19], (const float*)d_in[20],
        (const float*)d_in[25], (const float*)d_in[26]);
    dim3 g3(4, 2);
    k_exp_fc2<<<g3, 256, 0, stream>>>(hbuf,
        (const float*)d_in[15], (const float*)d_in[16],
        (const float*)d_in[21], (const float*)d_in[22],
        (const float*)d_in[27], (const float*)d_in[28], (float*)d_out);
}

// Round 2
// 392.968 us; speedup vs baseline: 1.0265x; 1.0225x over previous
//
#include <hip/hip_runtime.h>
#include <math.h>

#define DEV __device__ __forceinline__

static constexpr int S_LEN  = 2048;
static constexpr int IN_DIM = 1024;
static constexpr int P_DIM  = 512;
static constexpr int NHEAD  = 8;
static constexpr int HD     = 64;
static constexpr int KN     = 128;

typedef __attribute__((ext_vector_type(8))) short bf16x8;
typedef __attribute__((ext_vector_type(4))) float f32x4;

DEV float gelu_exact(float x) {
    return 0.5f * x * (1.0f + erff(x * 0.70710678118654752440f));
}

// float -> bf16 (RNE), and the split residual helpers
DEV short bf_hi(float x) {
    unsigned u = __float_as_uint(x);
    unsigned r = (u + 0x7fffu + ((u >> 16) & 1u)) >> 16;
    return (short)r;
}
DEV float bf_f(short h) { return __uint_as_float(((unsigned)(unsigned short)h) << 16); }

// 256-thread block sum reduction. sm4 must be float[4] shared.
DEV float block_reduce_sum(float v, float* sm4) {
    #pragma unroll
    for (int off = 32; off; off >>= 1) v += __shfl_down(v, off, 64);
    int lane = threadIdx.x & 63, w = threadIdx.x >> 6;
    __syncthreads();
    if (lane == 0) sm4[w] = v;
    __syncthreads();
    return sm4[0] + sm4[1] + sm4[2] + sm4[3];
}

// ---------------- K1: centroids, L2-normalized, split-bf16 [p][d] -----------
__global__ __launch_bounds__(256) void k_cent(const float* __restrict__ penta,
                                              short* __restrict__ ch,
                                              short* __restrict__ cl) {
    int p = blockIdx.x, t = threadIdx.x;
    __shared__ float sm4[4];
    float c0 = 0.f, c1 = 0.f;
    #pragma unroll
    for (int v = 0; v < 5; v++) {
        const float* row = penta + ((long)p * 5 + v) * P_DIM;
        c0 += row[t];
        c1 += row[t + 256];
    }
    c0 /= 5.0f; c1 /= 5.0f;
    float tot = block_reduce_sum(c0 * c0 + c1 * c1, sm4);
    float n = fmaxf(sqrtf(tot), 1e-12f);
    float v0 = c0 / n, v1 = c1 / n;
    short h0 = bf_hi(v0), h1 = bf_hi(v1);
    ch[p * P_DIM + t]       = h0;
    ch[p * P_DIM + t + 256] = h1;
    cl[p * P_DIM + t]       = bf_hi(v0 - bf_f(h0));
    cl[p * P_DIM + t + 256] = bf_hi(v1 - bf_f(h1));
}

// ---------------- weight transpose + split: W (K x N) -> WT_hi/lo (N x K) ---
template <int K, int N>
__global__ __launch_bounds__(256) void k_wt(const float* __restrict__ W,
                                            short* __restrict__ WTh,
                                            short* __restrict__ WTl) {
    __shared__ float tile[64][65];
    int bk = blockIdx.x, bn = blockIdx.y;
    int t = threadIdx.x;
    int c = t & 63, r4 = t >> 6;
    #pragma unroll
    for (int i = 0; i < 16; i++) {
        int row = r4 + i * 4;
        tile[row][c] = W[(long)(bk * 64 + row) * N + bn * 64 + c];
    }
    __syncthreads();
    #pragma unroll
    for (int i = 0; i < 16; i++) {
        int n = r4 + i * 4;
        float v = tile[c][n];
        short h = bf_hi(v);
        long o = (long)(bn * 64 + n) * K + bk * 64 + c;
        WTh[o] = h;
        WTl[o] = bf_hi(v - bf_f(h));
    }
}

// ---------------- MFMA split-bf16 GEMM: C = A@W + bias ----------------------
// BM x 128 block tile (BK=32), 4 waves in 2x2, wave tile (BM/2) x 64.
// Per-output-element accumulation order is independent of BM -> results are
// bit-identical across BM; BM=32 quadruples the grid vs BM=128 for occupancy.
template <int BM, int K, int N, int EPI, bool SPLITA>
__global__ __launch_bounds__(256) void k_mm(const float* __restrict__ Af,
                                            const short* __restrict__ Ash,
                                            const short* __restrict__ Asl,
                                            const short* __restrict__ BTh,
                                            const short* __restrict__ BTl,
                                            const float* __restrict__ bias,
                                            float* __restrict__ C,
                                            unsigned long long* __restrict__ rowkey) {
    constexpr int TI = (BM + 31) / 32;   // i-tiles (of 16 rows) per wave
    __shared__ short Ah[BM * 40], Al[BM * 40], Bh[128 * 40], Bl[128 * 40];
    int t = threadIdx.x;
    int lane = t & 63, wave = t >> 6;
    int wr = (wave >> 1) * (BM / 2), wc = (wave & 1) * 64;
    int m = lane & 15, quad = lane >> 4;
    int rb = blockIdx.x * BM, cb = blockIdx.y * 128;

    f32x4 acc[TI][4];
    #pragma unroll
    for (int i = 0; i < TI; i++)
        #pragma unroll
        for (int j = 0; j < 4; j++) acc[i][j] = (f32x4){0.f, 0.f, 0.f, 0.f};

    for (int k0 = 0; k0 < K; k0 += 32) {
        __syncthreads();
        if constexpr (SPLITA) {
            constexpr int TOT = BM * 4;           // float4 chunks per array
            #pragma unroll
            for (int ps = 0; ps < (TOT + 255) / 256; ps++) {
                int idx = t + ps * 256;
                if (idx < TOT) {
                    int row = idx >> 2, c4 = idx & 3;
                    *(float4*)(Ah + row * 40 + c4 * 8) =
                        *(const float4*)(Ash + (long)(rb + row) * K + k0 + c4 * 8);
                    *(float4*)(Al + row * 40 + c4 * 8) =
                        *(const float4*)(Asl + (long)(rb + row) * K + k0 + c4 * 8);
                }
            }
        } else {
            #pragma unroll
            for (int ps = 0; ps < BM / 32; ps++) {
                int row = (t >> 3) + ps * 32;
                int seg = t & 7;
                float4 v = *(const float4*)(Af + (long)(rb + row) * K + k0 + seg * 4);
                short h0 = bf_hi(v.x), h1 = bf_hi(v.y), h2 = bf_hi(v.z), h3 = bf_hi(v.w);
                short l0 = bf_hi(v.x - bf_f(h0)), l1 = bf_hi(v.y - bf_f(h1));
                short l2 = bf_hi(v.z - bf_f(h2)), l3 = bf_hi(v.w - bf_f(h3));
                *(short4*)(Ah + row * 40 + seg * 4) = make_short4(h0, h1, h2, h3);
                *(short4*)(Al + row * 40 + seg * 4) = make_short4(l0, l1, l2, l3);
            }
        }
        #pragma unroll
        for (int ps = 0; ps < 2; ps++) {
            int row = (t >> 2) + ps * 64;
            int seg = t & 3;
            *(float4*)(Bh + row * 40 + seg * 8) =
                *(const float4*)(BTh + (long)(cb + row) * K + k0 + seg * 8);
            *(float4*)(Bl + row * 40 + seg * 8) =
                *(const float4*)(BTl + (long)(cb + row) * K + k0 + seg * 8);
        }
        __syncthreads();

        bf16x8 ah[TI], al[TI], bh[4], bl[4];
        #pragma unroll
        for (int i = 0; i < TI; i++) {
            ah[i] = *(const bf16x8*)(Ah + (wr + i * 16 + m) * 40 + quad * 8);
            al[i] = *(const bf16x8*)(Al + (wr + i * 16 + m) * 40 + quad * 8);
        }
        #pragma unroll
        for (int j = 0; j < 4; j++) {
            bh[j] = *(const bf16x8*)(Bh + (wc + j * 16 + m) * 40 + quad * 8);
            bl[j] = *(const bf16x8*)(Bl + (wc + j * 16 + m) * 40 + quad * 8);
        }
        #pragma unroll
        for (int i = 0; i < TI; i++)
            #pragma unroll
            for (int j = 0; j < 4; j++) {
                acc[i][j] = __builtin_amdgcn_mfma_f32_16x16x32_bf16(ah[i], bh[j], acc[i][j], 0, 0, 0);
                acc[i][j] = __builtin_amdgcn_mfma_f32_16x16x32_bf16(ah[i], bl[j], acc[i][j], 0, 0, 0);
                acc[i][j] = __builtin_amdgcn_mfma_f32_16x16x32_bf16(al[i], bh[j], acc[i][j], 0, 0, 0);
            }
    }

    if (EPI == 0) {
        #pragma unroll
        for (int i = 0; i < TI; i++) {
            int gr0 = rb + wr + i * 16 + quad * 4;
            #pragma unroll
            for (int j = 0; j < 4; j++) {
                int gc = cb + wc + j * 16 + m;
                float bv = bias[gc];
                #pragma unroll
                for (int r = 0; r < 4; r++)
                    C[(long)(gr0 + r) * N + gc] = acc[i][j][r] + bv;
            }
        }
    } else {
        #pragma unroll
        for (int i = 0; i < TI; i++) {
            #pragma unroll
            for (int r = 0; r < 4; r++) {
                int gr = rb + wr + i * 16 + quad * 4 + r;
                float bv = acc[i][0][r];
                int bp = cb + wc + m;
                #pragma unroll
                for (int j = 1; j < 4; j++) {
                    float v = acc[i][j][r];
                    int p = cb + wc + j * 16 + m;   // ascending; > keeps lowest p
                    if (v > bv) { bv = v; bp = p; }
                }
                #pragma unroll
                for (int off = 1; off < 16; off <<= 1) {
                    float ov = __shfl_xor(bv, off, 64);
                    int op = __shfl_xor(bp, off, 64);
                    if (ov > bv || (ov == bv && op < bp)) { bv = ov; bp = op; }
                }
                if (m == 0) {
                    unsigned u = __float_as_uint(bv);
                    u = (u & 0x80000000u) ? ~u : (u | 0x80000000u);
                    unsigned long long key =
                        ((unsigned long long)u << 32) | (unsigned)(0xFFFFFFFFu - (unsigned)bp);
                    atomicMax(&rowkey[gr], key);
                }
            }
        }
    }
}

// ---------------- K3: LayerNorm -> gelu -> L2 norm -> emit SPLIT bf16 -------
__global__ __launch_bounds__(256) void k_ln_gelu_norm(const float* __restrict__ Zin,
                                                      const float* __restrict__ g,
                                                      const float* __restrict__ b,
                                                      short* __restrict__ z_h,
                                                      short* __restrict__ z_l) {
    long row = blockIdx.x;
    int t = threadIdx.x;
    __shared__ float sm4[4];
    float x0 = Zin[row * P_DIM + t], x1 = Zin[row * P_DIM + t + 256];
    float mu = block_reduce_sum(x0 + x1, sm4) * (1.0f / P_DIM);
    float d0 = x0 - mu, d1 = x1 - mu;
    float var = block_reduce_sum(d0 * d0 + d1 * d1, sm4) * (1.0f / P_DIM);
    float rs = 1.0f / sqrtf(var + 1e-5f);
    float y0 = gelu_exact(d0 * rs * g[t] + b[t]);
    float y1 = gelu_exact(d1 * rs * g[t + 256] + b[t + 256]);
    float nn = block_reduce_sum(y0 * y0 + y1 * y1, sm4);
    float n = fmaxf(sqrtf(nn), 1e-12f);
    float v0 = y0 / n, v1 = y1 / n;
    short h0 = bf_hi(v0), h1 = bf_hi(v1);
    z_h[row * P_DIM + t]       = h0;
    z_h[row * P_DIM + t + 256] = h1;
    z_l[row * P_DIM + t]       = bf_hi(v0 - bf_f(h0));
    z_l[row * P_DIM + t + 256] = bf_hi(v1 - bf_f(h1));
}

// ---------------- K5: bitonic argsort (fused rowkey->pos gather) ------------
// 1024 threads: 2 elements/thread/phase (was 8) to shrink the serial
// barrier-chain cost of the 66 bitonic phases on a 2-block launch.
__global__ __launch_bounds__(1024) void k_sort(const unsigned long long* __restrict__ rowkey,
                                               const float* __restrict__ spos,
                                               int* __restrict__ order,
                                               float* __restrict__ pos_srt) {
    int b = blockIdx.x, t = threadIdx.x;
    __shared__ unsigned long long key[2048];
    for (int u = 0; u < 2; u++) {
        int i = t + u * 1024;
        unsigned p = 0xFFFFFFFFu - (unsigned)(rowkey[b * 2048 + i] & 0xFFFFFFFFull);
        float pv = spos[p];
        key[i] = (((unsigned long long)__float_as_uint(pv)) << 32) | (unsigned)i;
    }
    __syncthreads();
    for (int k = 2; k <= 2048; k <<= 1) {
        for (int j = k >> 1; j > 0; j >>= 1) {
            for (int u = 0; u < 2; u++) {
                int i = t + u * 1024;
                int l = i ^ j;
                if (l > i) {
                    bool up = ((i & k) == 0);
                    unsigned long long a = key[i], c = key[l];
                    if ((a > c) == up) { key[i] = c; key[l] = a; }
                }
            }
            __syncthreads();
        }
    }
    for (int u = 0; u < 2; u++) {
        int r = t + u * 1024;
        unsigned long long kk = key[r];
        order[b * 2048 + r]   = (int)(kk & 0xffffffffu);
        pos_srt[b * 2048 + r] = __uint_as_float((unsigned)(kk >> 32));
    }
}

// ---------------- K6: exact top-128, one WAVE per query ---------------------
__global__ __launch_bounds__(256) void k_routes(const float* __restrict__ pos_srt,
                                                const int* __restrict__ order,
                                                unsigned long long* __restrict__ bmG,
                                                uint2* __restrict__ bounds) {
    int blk = blockIdx.x;                 // 1024 blocks, 4 queries (waves) each
    int b = blk >> 9;
    int t = threadIdx.x;
    int lane = t & 63, wave = t >> 6;
    int r = (blk & 511) * 4 + wave;       // query rank in [0,2048)
    __shared__ float ps[2048];
    __shared__ unsigned short tk[2048];
    for (int u = 0; u < 8; u++) {
        int i = t + u * 256;
        ps[i] = pos_srt[b * 2048 + i];
        tk[i] = (unsigned short)order[b * 2048 + i];
    }
    __syncthreads();

    float pi = ps[r];
    float T = 3e38f;
    #pragma unroll
    for (int a2 = 0; a2 < 2; a2++) {
        int a = lane + a2 * 64;           // 0..127
        int jl = r - a, jr = r + 127 - a;
        if (jl >= 0 && jr <= 2047) {
            float dl = (a > 0)   ? (pi - ps[jl]) : 0.f;
            float dr = (a < 127) ? (ps[jr] - pi) : 0.f;
            T = fminf(T, fmaxf(dl, dr));
        }
    }
    #pragma unroll
    for (int off = 1; off < 64; off <<= 1) T = fminf(T, __shfl_xor(T, off, 64));

    int lo = 0, hi = r;
    while (lo < hi) { int mid = (lo + hi) >> 1; if (pi - ps[mid] <= T) hi = mid; else lo = mid + 1; }
    int mn = lo;
    lo = r; hi = 2047;
    while (lo < hi) { int mid = (lo + hi + 1) >> 1; if (ps[mid] - pi <= T) lo = mid; else hi = mid - 1; }
    int mx = lo;
    int Ls, Rs;
    if (T > 0.f) {
        lo = 0; hi = r;
        while (lo < hi) { int mid = (lo + hi) >> 1; if (pi - ps[mid] < T) hi = mid; else lo = mid + 1; }
        Ls = lo;
        lo = r; hi = 2047;
        while (lo < hi) { int mid = (lo + hi + 1) >> 1; if (ps[mid] - pi < T) lo = mid; else hi = mid - 1; }
        Rs = lo;
    } else { Ls = r + 1; Rs = r - 1; }

    int cnt_strict = (Rs >= Ls) ? (Rs - Ls + 1) : 0;
    int need = 128 - cnt_strict;
    int l0a, l0b, r0a, r0b;
    if (cnt_strict > 0) { l0a = mn; l0b = Ls - 1; r0a = Rs + 1; r0b = mx; }
    else                { l0a = mn; l0b = mx;     r0a = 1;      r0b = 0; }
    int nL = (l0b >= l0a) ? (l0b - l0a + 1) : 0;
    int nR = (r0b >= r0a) ? (r0b - r0a + 1) : 0;
    int tiecount = nL + nR;

    int X = 65535;
    if (need < tiecount) {
        int lo2 = 0, hi2 = 2047;
        while (lo2 < hi2) {
            int mid = (lo2 + hi2) >> 1;
            int cnt = 0;
            for (int e = lane; e < tiecount; e += 64) {
                int j = (e < nL) ? (l0a + e) : (r0a + e - nL);
                cnt += (tk[j] <= mid) ? 1 : 0;
            }
            #pragma unroll
            for (int off = 1; off < 64; off <<= 1) cnt += __shfl_xor(cnt, off, 64);
            if (cnt >= need) hi2 = mid; else lo2 = mid + 1;
        }
        X = lo2;
    }

    int qlo_loc = 1 << 30, qhi_loc = -1;
    if (lane < 32) {
        unsigned long long bits = 0;
        int j0 = lane << 6, j1 = j0 + 63;
        if (cnt_strict > 0) {
            int a0 = max(Ls, j0), a1 = min(Rs, j1);
            if (a0 <= a1) {
                int s = a0 - j0, e = a1 - j0;
                unsigned long long msk = (e - s == 63) ? ~0ull
                                       : (((1ull << (e - s + 1)) - 1) << s);
                bits |= msk;
            }
        }
        int a0 = max(l0a, j0), a1 = min(l0b, j1);
        for (int j = a0; j <= a1; j++) if (tk[j] <= X) bits |= 1ull << (j - j0);
        a0 = max(r0a, j0); a1 = min(r0b, j1);
        for (int j = a0; j <= a1; j++) if (tk[j] <= X) bits |= 1ull << (j - j0);
        if (bits) {
            qlo_loc = j0 + __builtin_ctzll(bits);
            qhi_loc = j0 + 63 - __builtin_clzll(bits);
        }
        bmG[((long)(b * 2048 + r)) * 32 + lane] = bits;
    }
    #pragma unroll
    for (int off = 1; off < 64; off <<= 1) {
        qlo_loc = min(qlo_loc, __shfl_xor(qlo_loc, off, 64));
        qhi_loc = max(qhi_loc, __shfl_xor(qhi_loc, off, 64));
    }
    if (lane == 0)
        bounds[b * 2048 + r] = make_uint2((unsigned)qlo_loc, (unsigned)qhi_loc);
}

// ---------------- K6b: K prep — sorted, split bf16, [b][rank][512] ----------
__global__ __launch_bounds__(256) void k_kprep(const float* __restrict__ qkv,
                                               const int* __restrict__ order,
                                               short* __restrict__ Ks_h,
                                               short* __restrict__ Ks_l) {
    int b = blockIdx.y;
    int t = threadIdx.x;
    int lr = t >> 5;                       // 8 ranks per block
    int seg = t & 31;                      // 16 floats per seg
    int rank = blockIdx.x * 8 + lr;
    int tok = order[b * 2048 + rank];
    const float4* src = (const float4*)qkv + (long)(b * 2048 + tok) * 384 + 128 + seg * 4;
    long dsto = (long)(b * 2048 + rank) * 512 + seg * 16;
    #pragma unroll
    for (int u = 0; u < 4; u++) {
        float4 v = src[u];
        short h0 = bf_hi(v.x), h1 = bf_hi(v.y), h2 = bf_hi(v.z), h3 = bf_hi(v.w);
        *(short4*)(Ks_h + dsto + u * 4) = make_short4(h0, h1, h2, h3);
        *(short4*)(Ks_l + dsto + u * 4) =
            make_short4(bf_hi(v.x - bf_f(h0)), bf_hi(v.y - bf_f(h1)),
                        bf_hi(v.z - bf_f(h2)), bf_hi(v.w - bf_f(h3)));
    }
}

// ---------------- K6c: V prep — sorted, transposed bf16-hi, [b][d][rank] ----
__global__ __launch_bounds__(256) void k_vprep(const float* __restrict__ qkv,
                                               const int* __restrict__ order,
                                               short* __restrict__ Vt_h) {
    __shared__ short tile[64][72];
    int rt = blockIdx.x, dt = blockIdx.y, b = blockIdx.z;
    int t = threadIdx.x;
    int lr = t >> 2;                       // rank within tile
    int q4 = t & 3;
    int tok = order[b * 2048 + rt * 64 + lr];
    const float4* src = (const float4*)qkv + (long)(b * 2048 + tok) * 384 + 256 + dt * 16;
    #pragma unroll
    for (int u = 0; u < 4; u++) {
        float4 v = src[q4 + u * 4];
        int d0 = (q4 + u * 4) * 4;
        tile[d0 + 0][lr] = bf_hi(v.x);
        tile[d0 + 1][lr] = bf_hi(v.y);
        tile[d0 + 2][lr] = bf_hi(v.z);
        tile[d0 + 3][lr] = bf_hi(v.w);
    }
    __syncthreads();
    int d = t >> 2, c4 = t & 3;
    long o = ((long)(b * 512 + dt * 64 + d)) * 2048 + rt * 64 + c4 * 16;
    #pragma unroll
    for (int j = 0; j < 4; j++)
        *(short4*)(Vt_h + o + j * 4) = make_short4(tile[d][c4 * 16 + j * 4 + 0],
                                                   tile[d][c4 * 16 + j * 4 + 1],
                                                   tile[d][c4 * 16 + j * 4 + 2],
                                                   tile[d][c4 * 16 + j * 4 + 3]);
}

// ---------------- K7: MFMA flash attention (direct-global K/V) --------------
// Epilogue pools directly: z_att is only ever mean-pooled downstream, and
// mean(attn@W + b) = mean(attn)@W + b, so we atomicAdd per-dim sums into
// pooledZ and defer the 512x512 projection to k_opool (f32 weights).
__global__ __launch_bounds__(256) void k_attn(const float* __restrict__ qkv,
                                              const int* __restrict__ order,
                                              const unsigned long long* __restrict__ bmG,
                                              const uint2* __restrict__ bounds,
                                              const short* __restrict__ Ks_h,
                                              const short* __restrict__ Ks_l,
                                              const short* __restrict__ Vt_h,
                                              float* __restrict__ pooledZ) {
    __shared__ __align__(16) char smem[17280];
    short* Pt = (short*)smem;                               // 4 waves x 1280 shorts
    unsigned short* cm = (unsigned short*)(smem + 10240);   // 128 x 16
    float* Opart = (float*)smem;                            // alias: [2][16][128]
    float2* ml = (float2*)(smem + 16384);                   // [2][2][16]
    int* sh_tok = (int*)(smem + 16896);                     // 16
    int* sh_lohi = (int*)(smem + 16960);                    // 2
    float2* sc = (float2*)(smem + 16968);                   // [2][16] w0*inv, w1*inv

    int gb = blockIdx.x;
    int b  = gb >> 9;
    int qg = (gb >> 2) & 127;
    int hp = gb & 3;
    int h0 = hp * 2;
    int r0 = qg * 16;
    int t = threadIdx.x;
    int lane = t & 63, wave = t >> 6;
    int rh = wave & 1, hs = wave >> 1;
    int key = lane & 15, quad = lane >> 4;

    const float4* qkvF4 = (const float4*)qkv;

    if (t < 16) sh_tok[t] = order[b * 2048 + r0 + t];
    if (t == 0) { sh_lohi[0] = 1 << 30; sh_lohi[1] = 0; }
    #pragma unroll
    for (int u = 0; u < 8; u++) {
        int e = t + u * 256;
        int c = e >> 4, q = e & 15;
        cm[c * 16 + q] = (unsigned short)(
            (bmG[((long)(b * 2048 + r0 + q)) * 32 + (c >> 2)] >> ((c & 3) * 16)) & 0xFFFF);
    }
    __syncthreads();
    if (t < 16) {
        uint2 bd = bounds[b * 2048 + r0 + t];
        atomicMin(&sh_lohi[0], (int)bd.x);
        atomicMax(&sh_lohi[1], (int)bd.y);
    }

    bf16x8 qh[2], ql[2];
    {
        long tq = (long)(b * 2048 + sh_tok[key]) * 384;
        #pragma unroll
        for (int ks = 0; ks < 2; ks++) {
            float4 v0 = qkvF4[tq + (h0 + hs) * 16 + ks * 8 + quad * 2];
            float4 v1 = qkvF4[tq + (h0 + hs) * 16 + ks * 8 + quad * 2 + 1];
            float vv[8] = {v0.x, v0.y, v0.z, v0.w, v1.x, v1.y, v1.z, v1.w};
            #pragma unroll
            for (int j = 0; j < 8; j++) {
                short hb = bf_hi(vv[j]);
                qh[ks][j] = hb;
                ql[ks][j] = bf_hi(vv[j] - bf_f(hb));
            }
        }
    }
    __syncthreads();
    int lo = sh_lohi[0] & ~63, hi = sh_lohi[1] + 1;

    float mrow[4], lrow[4];
    f32x4 Ont[4];
    #pragma unroll
    for (int r = 0; r < 4; r++) { mrow[r] = -1e30f; lrow[r] = 0.f; }
    #pragma unroll
    for (int nt = 0; nt < 4; nt++) Ont[nt] = (f32x4){0.f, 0.f, 0.f, 0.f};

    short* PtH = Pt + wave * 1280;
    short* PtL = PtH + 640;

    int hd = h0 + hs;
    long kbase = ((long)b * 2048) * 512 + hd * 64 + quad * 8;   // + rank*512 + ks*32
    long vbase = ((long)(b * 512 + hd * 64 + key)) * 2048;      // + nt*16*2048 + rank

    // NOTE: no __syncthreads() in this loop — waves run fully independently.
    for (int c0 = lo; c0 < hi; c0 += 64) {
        int cb = c0 + rh * 32;
        if (cb >= hi) continue;                  // wave-uniform
        int ch0 = cb >> 4;
        unsigned long long m0 = *(const unsigned long long*)(cm + ch0 * 16 + quad * 4);
        unsigned long long m1 = (ch0 + 1 < 128)
            ? *(const unsigned long long*)(cm + (ch0 + 1) * 16 + quad * 4) : 0ull;
        if (!__any((m0 | m1) != 0ull)) continue; // wave-uniform skip

        // cb <= 2016 (multiple of 32, < hi <= 2048) so cb+31 <= 2047: in-bounds.
        long kr0 = kbase + (long)(cb + key) * 512;
        long kr1 = kbase + (long)(cb + 16 + key) * 512;

        f32x4 S0 = (f32x4){0.f,0.f,0.f,0.f}, S1 = (f32x4){0.f,0.f,0.f,0.f};
        #pragma unroll
        for (int ks = 0; ks < 2; ks++) {
            bf16x8 b0h = *(const bf16x8*)(Ks_h + kr0 + ks * 32);
            bf16x8 b0l = *(const bf16x8*)(Ks_l + kr0 + ks * 32);
            bf16x8 b1h = *(const bf16x8*)(Ks_h + kr1 + ks * 32);
            bf16x8 b1l = *(const bf16x8*)(Ks_l + kr1 + ks * 32);
            S0 = __builtin_amdgcn_mfma_f32_16x16x32_bf16(qh[ks], b0h, S0, 0, 0, 0);
            S0 = __builtin_amdgcn_mfma_f32_16x16x32_bf16(qh[ks], b0l, S0, 0, 0, 0);
            S0 = __builtin_amdgcn_mfma_f32_16x16x32_bf16(ql[ks], b0h, S0, 0, 0, 0);
            S1 = __builtin_amdgcn_mfma_f32_16x16x32_bf16(qh[ks], b1h, S1, 0, 0, 0);
            S1 = __builtin_amdgcn_mfma_f32_16x16x32_bf16(qh[ks], b1l, S1, 0, 0, 0);
            S1 = __builtin_amdgcn_mfma_f32_16x16x32_bf16(ql[ks], b1h, S1, 0, 0, 0);
        }
        float s0[4], s1[4], p0[4], p1[4];
        unsigned bit0[4], bit1[4];
        #pragma unroll
        for (int r = 0; r < 4; r++) {
            bit0[r] = (unsigned)((m0 >> (r * 16 + key)) & 1);
            bit1[r] = (unsigned)((m1 >> (r * 16 + key)) & 1);
            s0[r] = bit0[r] ? S0[r] * 0.125f : -1e30f;
            s1[r] = bit1[r] ? S1[r] * 0.125f : -1e30f;
        }
        #pragma unroll
        for (int r = 0; r < 4; r++) {
            float cmax = fmaxf(s0[r], s1[r]);
            cmax = fmaxf(cmax, __shfl_xor(cmax, 1, 64));
            cmax = fmaxf(cmax, __shfl_xor(cmax, 2, 64));
            cmax = fmaxf(cmax, __shfl_xor(cmax, 4, 64));
            cmax = fmaxf(cmax, __shfl_xor(cmax, 8, 64));
            float mn = fmaxf(mrow[r], cmax);
            float alpha = __expf(mrow[r] - mn);
            mrow[r] = mn;
            p0[r] = bit0[r] ? __expf(s0[r] - mn) : 0.f;
            p1[r] = bit1[r] ? __expf(s1[r] - mn) : 0.f;
            float rs = p0[r] + p1[r];
            rs += __shfl_xor(rs, 1, 64);
            rs += __shfl_xor(rs, 2, 64);
            rs += __shfl_xor(rs, 4, 64);
            rs += __shfl_xor(rs, 8, 64);
            lrow[r] = lrow[r] * alpha + rs;
            #pragma unroll
            for (int nt = 0; nt < 4; nt++) Ont[nt][r] *= alpha;
        }
        #pragma unroll
        for (int r = 0; r < 4; r++) {
            short ha = bf_hi(p0[r]);
            PtH[(quad * 4 + r) * 40 + key] = ha;
            PtL[(quad * 4 + r) * 40 + key] = bf_hi(p0[r] - bf_f(ha));
            short hb = bf_hi(p1[r]);
            PtH[(quad * 4 + r) * 40 + 16 + key] = hb;
            PtL[(quad * 4 + r) * 40 + 16 + key] = bf_hi(p1[r] - bf_f(hb));
        }
        bf16x8 pfh = *(const bf16x8*)(PtH + key * 40 + quad * 8);
        bf16x8 pfl = *(const bf16x8*)(PtL + key * 40 + quad * 8);
        #pragma unroll
        for (int nt = 0; nt < 4; nt++) {
            bf16x8 vf = *(const bf16x8*)(Vt_h + vbase + (long)nt * 16 * 2048
                                         + cb + quad * 8);
            Ont[nt] = __builtin_amdgcn_mfma_f32_16x16x32_bf16(pfh, vf, Ont[nt], 0, 0, 0);
            Ont[nt] = __builtin_amdgcn_mfma_f32_16x16x32_bf16(pfl, vf, Ont[nt], 0, 0, 0);
        }
    }

    if (key == 0) {
        #pragma unroll
        for (int r = 0; r < 4; r++)
            ml[(rh * 2 + hs) * 16 + quad * 4 + r] = make_float2(mrow[r], lrow[r]);
    }
    __syncthreads();   // all waves done with cm/Pt; Opart may now alias them
    #pragma unroll
    for (int nt = 0; nt < 4; nt++)
        #pragma unroll
        for (int r = 0; r < 4; r++)
            Opart[rh * 2048 + (quad * 4 + r) * 128 + hs * 64 + nt * 16 + key] = Ont[nt][r];

    // per-(q, head-half) combine weights
    if (t < 32) {
        int q = t >> 1, hs2 = t & 1;
        float2 a = ml[(0 * 2 + hs2) * 16 + q];
        float2 c = ml[(1 * 2 + hs2) * 16 + q];
        float M = fmaxf(a.x, c.x);
        float w0 = __expf(a.x - M), w1 = __expf(c.x - M);
        float inv = 1.0f / fmaxf(a.y * w0 + c.y * w1, 1e-37f);
        sc[hs2 * 16 + q] = make_float2(w0 * inv, w1 * inv);
    }
    __syncthreads();

    // reduce over the 16 queries of this block, one atomicAdd per dim
    if (t < 128) {
        int d = t, hs2 = d >> 6;
        float s = 0.f;
        #pragma unroll
        for (int q = 0; q < 16; q++) {
            float2 w = sc[hs2 * 16 + q];
            s += Opart[q * 128 + d] * w.x + Opart[2048 + q * 128 + d] * w.y;
        }
        atomicAdd(&pooledZ[b * P_DIM + h0 * HD + d], s);
    }
}

// ---------------- K8: pooled out-projection (tiny mat-vec, f32 weights) -----
// pooled[b][n] = sum_d pooledZ[b][d] * outW[d][n] + S_LEN * outb[n]
// (k_exp_fc1 divides by S_LEN, matching reference mean(z_att) @ w1 chain)
__global__ __launch_bounds__(256) void k_opool(const float* __restrict__ pooledZ,
                                               const float* __restrict__ outW,
                                               const float* __restrict__ outb,
                                               float* __restrict__ pooled) {
    int b = blockIdx.y, t = threadIdx.x;
    int c = blockIdx.x * 256 + t;
    __shared__ float pz[P_DIM];
    pz[t]       = pooledZ[b * P_DIM + t];
    pz[t + 256] = pooledZ[b * P_DIM + t + 256];
    __syncthreads();
    float acc = 0.f;
    #pragma unroll 8
    for (int d = 0; d < P_DIM; d++) acc = fmaf(pz[d], outW[d * P_DIM + c], acc);
    pooled[b * P_DIM + c] = acc + (float)S_LEN * outb[c];
}

// ---------------- Expert stage 1: h = pooled/S @ w1 + b1 (all 3 experts) ----
__global__ __launch_bounds__(256) void k_exp_fc1(const float* __restrict__ pooled,
                                                 const float* __restrict__ w1_0, const float* __restrict__ b1_0,
                                                 const float* __restrict__ w1_1, const float* __restrict__ b1_1,
                                                 const float* __restrict__ w1_2, const float* __restrict__ b1_2,
                                                 float* __restrict__ h) {
    int t = threadIdx.x, b = blockIdx.y;
    int c = blockIdx.x * 256 + t;  // [0, 1792)
    __shared__ float pl[P_DIM];
    pl[t]       = pooled[b * P_DIM + t]       * (1.0f / S_LEN);
    pl[t + 256] = pooled[b * P_DIM + t + 256] * (1.0f / S_LEN);
    __syncthreads();

    const float* wp; const float* bp; int s2, j;
    if (c < 256)      { wp = w1_0; bp = b1_0; s2 = 256;  j = c; }
    else if (c < 768) { wp = w1_1; bp = b1_1; s2 = 512;  j = c - 256; }
    else              { wp = w1_2; bp = b1_2; s2 = 1024; j = c - 768; }

    const float* p = wp + j;
    float acc = 0.f;
    #pragma unroll 16
    for (int k = 0; k < P_DIM; k++) {
        acc = fmaf(pl[k], *p, acc);
        p += s2;
    }
    h[(long)b * 1792 + c] = acc + bp[j];
}

// ---------------- Expert stage 2: LN + gelu per (expert, batch) -------------
__global__ __launch_bounds__(256) void k_exp_ln(float* __restrict__ h,
                                                const float* __restrict__ g0, const float* __restrict__ bb0,
                                                const float* __restrict__ g1, const float* __restrict__ bb1,
                                                const float* __restrict__ g2, const float* __restrict__ bb2) {
    int e = blockIdx.x, b = blockIdx.y, t = threadIdx.x;
    __shared__ float sm4[4];
    const int offs[3] = {0, 256, 768};
    const int ns[3]   = {256, 512, 1024};
    const float* gs[3]  = {g0, g1, g2};
    const float* bbs[3] = {bb0, bb1, bb2};
    int n = ns[e];
    float* hp = h + (long)b * 1792 + offs[e];
    const float* g = gs[e]; const float* bb = bbs[e];

    float x[4];
    float loc = 0.f;
    for (int u = 0; u < 4; u++) {
        int j = t + u * 256;
        x[u] = (j < n) ? hp[j] : 0.f;
        loc += x[u];
    }
    float mu = block_reduce_sum(loc, sm4) / (float)n;
    loc = 0.f;
    for (int u = 0; u < 4; u++) {
        int j = t + u * 256;
        if (j < n) { float d = x[u] - mu; loc += d * d; }
    }
    float var = block_reduce_sum(loc, sm4) / (float)n;
    float rs = 1.0f / sqrtf(var + 1e-5f);
    for (int u = 0; u < 4; u++) {
        int j = t + u * 256;
        if (j < n) hp[j] = gelu_exact((x[u] - mu) * rs * g[j] + bb[j]);
    }
}

// ---------------- Expert stage 3: out = h @ w2 + b2 (all 3 experts) ---------
__global__ __launch_bounds__(256) void k_exp_fc2(const float* __restrict__ h,
                                                 const float* __restrict__ w2_0, const float* __restrict__ b2_0,
                                                 const float* __restrict__ w2_1, const float* __restrict__ b2_1,
                                                 const float* __restrict__ w2_2, const float* __restrict__ b2_2,
                                                 float* __restrict__ out) {
    int t = threadIdx.x, b = blockIdx.y;
    int c = blockIdx.x * 256 + t;  // [0, 1024), valid < 896
    __shared__ float hs[1792];
    for (int u = 0; u < 7; u++) hs[t + u * 256] = h[(long)b * 1792 + t + u * 256];
    __syncthreads();
    if (c >= 896) return;

    const float* wp; const float* bp; int s2, sN, j, off_h;
    if (c < 128)      { wp = w2_0; bp = b2_0; s2 = 256;  sN = 128; j = c;       off_h = 0; }
    else if (c < 384) { wp = w2_1; bp = b2_1; s2 = 512;  sN = 256; j = c - 128; off_h = 256; }
    else              { wp = w2_2; bp = b2_2; s2 = 1024; sN = 512; j = c - 384; off_h = 768; }

    const float* p = wp + j;
    const float* hh = hs + off_h;
    float acc = 0.f;
    #pragma unroll 16
    for (int k = 0; k < s2; k++) {
        acc = fmaf(hh[k], *p, acc);
        p += sN;
    }
    out[b * 896 + c] = acc + bp[j];
}

// ---------------------------------------------------------------------------
extern "C" void kernel_launch(void* const* d_in, const int* in_sizes, int n_in,
                              void* d_out, int out_size, void* d_ws, size_t ws_size,
                              hipStream_t stream) {
    const float* seq   = (const float*)d_in[0];
    const float* penta = (const float*)d_in[1];
    const float* spos  = (const float*)d_in[2];
    const float* projW = (const float*)d_in[3];
    const float* projb = (const float*)d_in[4];
    const float* lng   = (const float*)d_in[5];
    const float* lnb   = (const float*)d_in[6];
    const float* qkvW  = (const float*)d_in[7];
    const float* qkvb  = (const float*)d_in[8];
    const float* outW  = (const float*)d_in[9];
    const float* outb  = (const float*)d_in[10];

    float* ws      = (float*)d_ws;
    float* z_pre   = ws;                      // 2097152 floats (Ks alias)
    short* z_h     = (short*)(z_pre + 2097152); // 2097152 shorts
    short* z_l     = z_h + 2097152;           // 2097152 shorts
    float* qkv     = (float*)(z_l + 2097152); // 6291456 floats
    float* pooledZ = qkv + 6291456;           // 1024 (in old 'pos' slot)
    float* pooled  = pooledZ + 4096;          // 1024
    float* hbuf    = pooled + 1024;           // 4096
    unsigned long long* rowkey = (unsigned long long*)(hbuf + 4096);  // 4096 ull
    float* pos_srt = (float*)(rowkey + 4096); // 4096
    int*   order   = (int*)(pos_srt + 4096);  // 4096
    uint2* bounds  = (uint2*)(order + 4096);  // 4096 uint2
    unsigned long long* bmG = (unsigned long long*)(bounds + 4096); // 131072 ull
    short* cent_h  = (short*)(bmG + 131072);  // 524288 shorts
    short* cent_l  = cent_h + 524288;
    short* pjWT_h  = cent_l + 524288;         // 512x1024
    short* pjWT_l  = pjWT_h + 524288;
    short* qkWT_h  = pjWT_l + 524288;         // 1536x512
    short* qkWT_l  = qkWT_h + 786432;

    // K/V prep buffers (alias dead regions):
    //   Ks_h/Ks_l  <- z_pre (8 MB): dead after k_ln_gelu_norm (nothing writes
    //                it afterwards — out-proj GEMM is gone).
    //   Vt_h       <- cent_h..cent_l (2 MB): dead after anchor GEMM.
    short* Ks_h = (short*)z_pre;              // 2 x 2048 x 512
    short* Ks_l = Ks_h + 2097152;
    short* Vt_h = cent_h;                     // 2 x 512 x 2048

    // weight prep
    k_cent<<<1024, 256, 0, stream>>>(penta, cent_h, cent_l);
    { dim3 g(16, 8);  k_wt<IN_DIM, P_DIM><<<g, 256, 0, stream>>>(projW, pjWT_h, pjWT_l); }
    { dim3 g(8, 24);  k_wt<P_DIM, 3 * P_DIM><<<g, 256, 0, stream>>>(qkvW, qkWT_h, qkWT_l); }

    // proj -> ln/gelu/norm (emits pre-split z)
    { dim3 g(128, 4); k_mm<32, IN_DIM, P_DIM, 0, false><<<g, 256, 0, stream>>>(
          seq, nullptr, nullptr, pjWT_h, pjWT_l, projb, z_pre, nullptr); }
    k_ln_gelu_norm<<<4096, 256, 0, stream>>>(z_pre, lng, lnb, z_h, z_l);

    // anchor argmax -> sort (fused position gather)
    hipMemsetAsync(rowkey, 0, 4096 * sizeof(unsigned long long), stream);
    hipMemsetAsync(pooledZ, 0, 1024 * sizeof(float), stream);
    { dim3 g(128, 8); k_mm<32, P_DIM, 1024, 1, true><<<g, 256, 0, stream>>>(
          nullptr, z_h, z_l, cent_h, cent_l, nullptr, nullptr, rowkey); }
    k_sort<<<2, 1024, 0, stream>>>(rowkey, spos, order, pos_srt);

    // qkv -> routes(bitmap) -> K/V prep -> attention (pools directly)
    { dim3 g(128, 12); k_mm<32, P_DIM, 3 * P_DIM, 0, true><<<g, 256, 0, stream>>>(
          nullptr, z_h, z_l, qkWT_h, qkWT_l, qkvb, qkv, nullptr); }
    k_routes<<<1024, 256, 0, stream>>>(pos_srt, order, bmG, bounds);
    { dim3 g(256, 2); k_kprep<<<g, 256, 0, stream>>>(qkv, order, Ks_h, Ks_l); }
    { dim3 g(32, 8, 2); k_vprep<<<g, 256, 0, stream>>>(qkv, order, Vt_h); }
    k_attn<<<1024, 256, 0, stream>>>(qkv, order, bmG, bounds,
                                     Ks_h, Ks_l, Vt_h, pooledZ);

    // pooled out-projection + experts
    { dim3 g(2, 2); k_opool<<<g, 256, 0, stream>>>(pooledZ, outW, outb, pooled); }

    dim3 g1(7, 2);
    k_exp_fc1<<<g1, 256, 0, stream>>>(pooled,
        (const float*)d_in[11], (const float*)d_in[12],
        (const float*)d_in[17], (const float*)d_in[18],
        (const float*)d_in[23], (const float*)d_in[24], hbuf);
    dim3 g2(3, 2);
    k_exp_ln<<<g2, 256, 0, stream>>>(hbuf,
        (const float*)d_in[13], (const float*)d_in[14],
        (const float*)d_in[19], (const float*)d_in[20],
        (const float*)d_in[25], (const float*)d_in[26]);
    dim3 g3(4, 2);
    k_exp_fc2<<<g3, 256, 0, stream>>>(hbuf,
        (const float*)d_in[15], (const float*)d_in[16],
        (const float*)d_in[21], (const float*)d_in[22],
        (const float*)d_in[27], (const float*)d_in[28], (float*)d_out);
}